// Round 12
// baseline (6996.361 us; speedup 1.0000x reference)
//
#include <hip/hip_runtime.h>
#include <cstdint>
#include <cstddef>

#pragma clang fp contract(off)

// ===================== round-to-round toggles =====================
#define PRNG_PARTITIONABLE 1   // confirmed correct in R1 (absmax 0.0)
// sigmoid exp-form; tanh = XLA poly clamp +-9 (UNFUSED mul+add); gemms =
// sequential-k fmaf; score reduce = strict sequential per (b,s) lane;
// mask compaction (R7); fdiv_rn (R6/R8/R11 on-device bit-exact).
// R12: VOP3P retry isolating R6's confound (R6 also narrowed e4 loads to
// 8B — that was the regression, not pk). P4 tanh poly + P1 gate chains in
// v_pk_*_f32 (per-element IEEE identical); float4 e4 loads KEPT; dec_s
// split from v_s so pk pairs load contiguously. VGPR headroom to 128 free
// (grid caps occupancy at 2 blocks/CU).
// ==================================================================

#define INFTY_F 1.0e8f
#define TINY_F 1.17549435e-38f

typedef float f32x2 __attribute__((ext_vector_type(2)));

// ---------------- packed f32 VOP3P helpers (untied outputs) ----------------
__device__ __forceinline__ f32x2 pk_mul(f32x2 a, f32x2 b) {
  f32x2 d;
  asm("v_pk_mul_f32 %0, %1, %2" : "=v"(d) : "v"(a), "v"(b));
  return d;
}
__device__ __forceinline__ f32x2 pk_add(f32x2 a, f32x2 b) {
  f32x2 d;
  asm("v_pk_add_f32 %0, %1, %2" : "=v"(d) : "v"(a), "v"(b));
  return d;
}
__device__ __forceinline__ f32x2 pk_fma(f32x2 a, f32x2 b, f32x2 c) {
  f32x2 d;
  asm("v_pk_fma_f32 %0, %1, %2, %3" : "=v"(d) : "v"(a), "v"(b), "v"(c));
  return d;
}
__device__ __forceinline__ f32x2 pk2(float c) { f32x2 r; r.x = c; r.y = c; return r; }

// In-range correctly-rounded f32 divide: LLVM's FDIV32 lowering minus
// div_scale/div_fixup (pass-through for normal mid-range operands; here
// q in [4.9e-3, 53], |num| <= 500). On-device bit-exact R6/R8/R11.
__device__ __forceinline__ float fdiv_rn(float n, float q) {
  float y0 = __builtin_amdgcn_rcpf(q);
  float y  = fmaf(fmaf(-q, y0, 1.0f), y0, y0);
  float r0 = n * y;
  float e0 = fmaf(-q, r0, n);
  float r1 = fmaf(e0, y, r0);
  float e1 = fmaf(-q, r1, n);
  return fmaf(e1, y, r1);
}

// ---------------- threefry2x32 (jax exact) ----------------
__device__ __forceinline__ void tf2x32(uint32_t k0, uint32_t k1, uint32_t x0, uint32_t x1,
                                       uint32_t& o0, uint32_t& o1) {
  uint32_t ks2 = k0 ^ k1 ^ 0x1BD11BDAu;
  uint32_t v0 = x0 + k0, v1 = x1 + k1;
#define TF_R(r) { v0 += v1; v1 = (v1 << (r)) | (v1 >> (32 - (r))); v1 ^= v0; }
  TF_R(13) TF_R(15) TF_R(26) TF_R(6)
  v0 += k1;  v1 += ks2 + 1u;
  TF_R(17) TF_R(29) TF_R(16) TF_R(24)
  v0 += ks2; v1 += k0 + 2u;
  TF_R(13) TF_R(15) TF_R(26) TF_R(6)
  v0 += k0;  v1 += k1 + 3u;
  TF_R(17) TF_R(29) TF_R(16) TF_R(24)
  v0 += k1;  v1 += ks2 + 4u;
  TF_R(13) TF_R(15) TF_R(26) TF_R(6)
  v0 += ks2; v1 += k0 + 5u;
#undef TF_R
  o0 = v0; o1 = v1;
}

__device__ __forceinline__ uint32_t random_bits32(uint32_t k0, uint32_t k1, uint32_t j) {
#if PRNG_PARTITIONABLE
  uint32_t o0, o1;
  tf2x32(k0, k1, 0u, j, o0, o1);
  return o0 ^ o1;
#else
  uint32_t o0, o1;
  if (j < 131072u) { tf2x32(k0, k1, j, j + 131072u, o0, o1); return o0; }
  else             { tf2x32(k0, k1, j - 131072u, j, o0, o1); return o1; }
#endif
}

// ---------------- XLA math replicas ----------------
__device__ __forceinline__ float xla_tanhf(float x) {
  float xc = fminf(fmaxf(x, -9.0f), 9.0f);
  float x2 = xc * xc;
  float p = -2.76076847742355e-16f;
  p = (p * x2) + 2.00018790482477e-13f;
  p = (p * x2) + -8.60467152213735e-11f;
  p = (p * x2) + 5.12229709037114e-08f;
  p = (p * x2) + 1.48572235717979e-05f;
  p = (p * x2) + 6.37261928875436e-04f;
  p = (p * x2) + 4.89352455891786e-03f;
  float num = xc * p;
  float q = 1.19825839466702e-06f;
  q = (q * x2) + 1.18534705686654e-04f;
  q = (q * x2) + 2.26843463243900e-03f;
  q = (q * x2) + 4.89352518554385e-03f;
  float r = fdiv_rn(num, q);           // q in [4.9e-3, 53]: verified range
  return (fabsf(x) < 0.0004f) ? x : r;
}

// packed-pair tanh for P4: per-element ops IEEE-identical to xla_tanhf
// (v_pk_mul/v_pk_add are per-half IEEE mul/add; unfused chain preserved;
// div = fdiv_rn; clamps/selects scalar). Coefficient pairs are
// loop-invariant -> LICM hoists their materialization out of the m-loop.
__device__ __forceinline__ f32x2 tanh2pk(f32x2 x) {
  f32x2 xc;
  xc.x = fminf(fmaxf(x.x, -9.0f), 9.0f);
  xc.y = fminf(fmaxf(x.y, -9.0f), 9.0f);
  f32x2 x2 = pk_mul(xc, xc);
  f32x2 p = pk2(-2.76076847742355e-16f);
  p = pk_add(pk_mul(p, x2), pk2(2.00018790482477e-13f));
  p = pk_add(pk_mul(p, x2), pk2(-8.60467152213735e-11f));
  p = pk_add(pk_mul(p, x2), pk2(5.12229709037114e-08f));
  p = pk_add(pk_mul(p, x2), pk2(1.48572235717979e-05f));
  p = pk_add(pk_mul(p, x2), pk2(6.37261928875436e-04f));
  p = pk_add(pk_mul(p, x2), pk2(4.89352455891786e-03f));
  f32x2 num = pk_mul(xc, p);
  f32x2 q = pk2(1.19825839466702e-06f);
  q = pk_add(pk_mul(q, x2), pk2(1.18534705686654e-04f));
  q = pk_add(pk_mul(q, x2), pk2(2.26843463243900e-03f));
  q = pk_add(pk_mul(q, x2), pk2(4.89352518554385e-03f));
  f32x2 r;
  r.x = fdiv_rn(num.x, q.x);
  r.y = fdiv_rn(num.y, q.y);
  r.x = (fabsf(x.x) < 0.0004f) ? x.x : r.x;
  r.y = (fabsf(x.y) < 0.0004f) ? x.y : r.y;
  return r;
}

__device__ __forceinline__ float xla_expf(float x) {
  x = fminf(x, 88.3762626647950f);
  x = fmaxf(x, -88.3762626647949f);
  float m = floorf((x * 1.44269504088896341f) + 0.5f);
  float r = x - (m * 0.693359375f);
  r = r - (m * -2.12194440e-4f);
  float r2 = r * r;
  float y = 1.9875691500E-4f;
  y = (y * r) + 1.3981999507E-3f;
  y = (y * r) + 8.3334519073E-3f;
  y = (y * r) + 4.1665795894E-2f;
  y = (y * r) + 1.6666665459E-1f;
  y = (y * r) + 5.0000001201E-1f;
  y = (y * r2) + r;
  y = y + 1.0f;
  int mi = (int)m;
  float s = __uint_as_float((uint32_t)((mi + 127) << 23));
  return y * s;
}

__device__ __forceinline__ float xla_sigmoidf(float x) {
  return 1.0f / (1.0f + xla_expf(-x));   // keep compiler div (denom can be huge)
}

__device__ __forceinline__ float xla_logf(float x) {
  uint32_t b = __float_as_uint(x);
  float e = (float)((int)(b >> 23) - 126);
  float m = __uint_as_float((b & 0x007fffffu) | 0x3f000000u);
  bool mlt = (m < 0.707106781186547524f);
  float tmp = mlt ? m : 0.0f;
  e = e - (mlt ? 1.0f : 0.0f);
  float xx = (m - 1.0f) + tmp;
  float z = xx * xx;
  float y = 7.0376836292E-2f;
  y = (y * xx) + -1.1514610310E-1f;
  y = (y * xx) + 1.1676998740E-1f;
  y = (y * xx) + -1.2420140846E-1f;
  y = (y * xx) + 1.4249322787E-1f;
  y = (y * xx) + -1.6668057665E-1f;
  y = (y * xx) + 2.0000714765E-1f;
  y = (y * xx) + -2.4999993993E-1f;
  y = (y * xx) + 3.3333331174E-1f;
  y = y * xx;
  y = y * z;
  y = y + (e * -2.12194440e-4f);
  y = y - (z * 0.5f);
  float res = xx + y;
  res = res + (e * 0.693359375f);
  return res;
}

__device__ __forceinline__ float gumbel_from_bits(uint32_t bits) {
  float f = __uint_as_float((bits >> 9) | 0x3f800000u) - 1.0f;
  float u = (f * 1.0f) + TINY_F;
  u = fmaxf(TINY_F, u);
  return -xla_logf(-xla_logf(u));
}

// ---------------- prep kernels ----------------
__global__ void k_keys(uint32_t* __restrict__ keys) {
  int t = threadIdx.x;
  if (t >= 128) return;
#if PRNG_PARTITIONABLE
  uint32_t o0, o1;
  tf2x32(0u, 1234u, 0u, (uint32_t)t, o0, o1);
  keys[2 * t] = o0; keys[2 * t + 1] = o1;
#else
  uint32_t o0, o1, a, bb;
  if (t < 64) {
    tf2x32(0u, 1234u, (uint32_t)(2 * t),     (uint32_t)(128 + 2 * t), o0, o1); a  = o0;
    tf2x32(0u, 1234u, (uint32_t)(2 * t + 1), (uint32_t)(129 + 2 * t), o0, o1); bb = o0;
  } else {
    tf2x32(0u, 1234u, (uint32_t)(2 * t - 128), (uint32_t)(2 * t),     o0, o1); a  = o1;
    tf2x32(0u, 1234u, (uint32_t)(2 * t - 127), (uint32_t)(2 * t + 1), o0, o1); bb = o1;
  }
  keys[2 * t] = a; keys[2 * t + 1] = bb;
#endif
}

__global__ void k_trans(const float* __restrict__ Wih, const float* __restrict__ Whh,
                        float* __restrict__ WihT, float* __restrict__ WhhT) {
  int idx = blockIdx.x * blockDim.x + threadIdx.x;
  if (idx < 65536) {
    int r = idx >> 7, k = idx & 127;
    WihT[k * 512 + r] = Wih[idx];
    WhhT[k * 512 + r] = Whh[idx];
  }
}

// enc_term[b][s][m] = sum_n enc[b][s][n] * Wref[m][n], sequential-n fmaf.
__global__ __launch_bounds__(128) void k_encT(const float* __restrict__ enc,
                                              const float* __restrict__ Wref,
                                              float* __restrict__ encT) {
  __shared__ float el[64 * 132];
  __shared__ float ot[64 * 129];
  int tid = threadIdx.x;
  int b  = blockIdx.x >> 1;
  int sh = blockIdx.x & 1;
  const float* eb = enc + (size_t)b * 16384 + (size_t)sh * 8192;
  for (int i = tid; i < 8192; i += 128) {
    int s = i >> 7, n = i & 127;
    el[s * 132 + n] = eb[i];
  }
  __syncthreads();
  int sl = tid & 63;
  int mh = tid >> 6;
  for (int ml = 0; ml < 64; ++ml) {
    int m = mh * 64 + ml;
    const float4* wr = (const float4*)(Wref + m * 128);   // wave-broadcast reads
    float acc = 0.0f;
#pragma unroll 8
    for (int q = 0; q < 32; ++q) {
      float4 w4 = wr[q];
      float4 e4 = *(const float4*)&el[sl * 132 + 4 * q];
      acc = fmaf(e4.x, w4.x, acc); acc = fmaf(e4.y, w4.y, acc);
      acc = fmaf(e4.z, w4.z, acc); acc = fmaf(e4.w, w4.w, acc);
    }
    ot[sl * 129 + m] = acc;
  }
  __syncthreads();
  float* op = encT + (size_t)b * 16384 + (size_t)(sh * 64) * 128;
  for (int i = tid; i < 8192; i += 128)
    op[i] = ot[(i >> 7) * 129 + (i & 127)];
}

// ---------------- main decode kernel (4 batches/block, 2 waves/batch) -------
__global__ __launch_bounds__(512, 4) void k_main(
    const float* __restrict__ enc, const float* __restrict__ h0,
    const float* __restrict__ c0, const float* __restrict__ dec_first,
    const float* __restrict__ W_out, const float* __restrict__ v,
    const float* __restrict__ b_ih, const float* __restrict__ b_hh,
    const float* __restrict__ WihT, const float* __restrict__ WhhT,
    const float* __restrict__ encT, const uint32_t* __restrict__ keys,
    float* __restrict__ out) {
  // xI[k][0..3] = inp[g][k], xI[k][4..7] = h[g][k]  (broadcast-read in P1/P3)
  __shared__ __align__(16) float xI_s[128][8];
  __shared__ float c_s[4][128];
  __shared__ float gates_s[4][512];
  __shared__ __align__(16) float dec_s[4][128];   // dec only (contiguous pairs)
  __shared__ float bih_s[512];
  __shared__ float bhh_s[512];
  __shared__ __align__(16) float v_s[128];
  __shared__ uint32_t keys_s[256];
  __shared__ int cu_s[4][128];         // compact list of unmasked positions
  __shared__ int pos_s[4][128];        // inverse: pos_s[g][s] = index in cu_s
  __shared__ float red_va[4][2];
  __shared__ int   red_ia[4][2];
  __shared__ float red_mx[4][2];
  __shared__ float red_se[4][2];
  __shared__ float red_msel[4];

  const int tid  = threadIdx.x;
  const int lane = tid & 63;
  const int w    = tid >> 6;         // wave 0..7
  const int g4   = w >> 1;           // batch slot for P4 (2 waves per batch)
  const int half = w & 1;            // list-half this wave owns
  const int s4   = half * 64 + lane; // this lane's list index / copy position
  const int bbase = blockIdx.x * 4;
  const int b4   = bbase + g4;

  // ---- init ----
  bih_s[tid] = b_ih[tid];
  bhh_s[tid] = b_hh[tid];
  if (tid < 256) keys_s[tid] = keys[tid];
  if (tid < 128) v_s[tid] = v[tid];
  {
    int g = tid >> 7, j = tid & 127;
    xI_s[j][g]     = dec_first[j];
    xI_s[j][4 + g] = h0[(size_t)(bbase + g) * 128 + j];
    c_s[g][j] = c0[(size_t)(bbase + g) * 128 + j];
    cu_s[g][j] = j;
    pos_s[g][j] = j;
  }
  float logp_sum = 0.0f;
  float* tour = out + 2048;
  __syncthreads();

  for (int step = 0; step < 128; ++step) {
    // ---- P1: gates = ((inp@WihT + b_ih) + h@WhhT) + b_hh, sequential-k fmaf
    // 4 pk_fma chains (batch pairs 01/23); per-element fmaf preserved.
    {
      const int r = tid;
      f32x2 aA01 = {0.0f, 0.0f}, aA23 = {0.0f, 0.0f};
      f32x2 aB01 = {0.0f, 0.0f}, aB23 = {0.0f, 0.0f};
      const float* pih = WihT + r;
      const float* phh = WhhT + r;
#pragma unroll 8
      for (int k = 0; k < 128; ++k) {
        float4 xi = *(const float4*)&xI_s[k][0];
        float4 xh = *(const float4*)&xI_s[k][4];
        float wih = pih[k * 512], whh = phh[k * 512];
        f32x2 wi2; wi2.x = wih; wi2.y = wih;
        f32x2 wh2; wh2.x = whh; wh2.y = whh;
        f32x2 xi01; xi01.x = xi.x; xi01.y = xi.y;
        f32x2 xi23; xi23.x = xi.z; xi23.y = xi.w;
        f32x2 xh01; xh01.x = xh.x; xh01.y = xh.y;
        f32x2 xh23; xh23.x = xh.z; xh23.y = xh.w;
        aA01 = pk_fma(xi01, wi2, aA01);
        aA23 = pk_fma(xi23, wi2, aA23);
        aB01 = pk_fma(xh01, wh2, aB01);
        aB23 = pk_fma(xh23, wh2, aB23);
      }
      float b1 = bih_s[r], b2 = bhh_s[r];
      gates_s[0][r] = (((aA01.x + b1) + aB01.x) + b2);
      gates_s[1][r] = (((aA01.y + b1) + aB01.y) + b2);
      gates_s[2][r] = (((aA23.x + b1) + aB23.x) + b2);
      gates_s[3][r] = (((aA23.y + b1) + aB23.y) + b2);
    }
    __syncthreads();

    // ---- P2: LSTM cell (exact op order), one (g,j) per thread
    {
      int g = tid >> 7, j = tid & 127;
      float gi = gates_s[g][j], gf = gates_s[g][128 + j];
      float gg = gates_s[g][256 + j], go = gates_s[g][384 + j];
      float si = xla_sigmoidf(gi), sf = xla_sigmoidf(gf), so = xla_sigmoidf(go);
      float gt = xla_tanhf(gg);
      float cold = c_s[g][j];
      float cn = (sf * cold) + (si * gt);
      c_s[g][j] = cn;
      xI_s[j][4 + g] = so * xla_tanhf(cn);
    }
    __syncthreads();

    // ---- P3: dec[g][m] = sum_k h[g][k]*W_out[k][m], sequential-k fmaf
    {
      int g = tid >> 7, m = tid & 127;
      float acc = 0.0f;
      const float* wo = W_out + m;
#pragma unroll 8
      for (int k = 0; k < 128; ++k)
        acc = fmaf(xI_s[k][4 + g], wo[k * 128], acc);
      dec_s[g][m] = acc;
    }
    __syncthreads();

    // ---- P4: scores over COMPACTED unmasked list / gumbel / argmax / logp
    const int u = 128 - step;          // unmasked count (uniform)
    const bool active = (s4 < u);      // whole wave inactive => exec-skip loop
    float masked = -INFTY_F;
    float val = -INFTY_F;
    int   ia = 0x7fffffff;
    int   sc = 0;
    if (active) {
      sc = cu_s[g4][s4];
      // gumbel first: pure ALU, overlaps the first e4 load window
      uint32_t kk0 = keys_s[2 * step], kk1 = keys_s[2 * step + 1];
      uint32_t j0 = (uint32_t)b4 * 128u + (uint32_t)sc;
      float gmb = gumbel_from_bits(random_bits32(kk0, kk1, j0));
      const float* ep = encT + ((size_t)b4 * 128 + (size_t)sc) * 128;
      float acc = 0.0f;
#pragma unroll 8
      for (int m4 = 0; m4 < 32; ++m4) {
        float4 e4 = *(const float4*)&ep[4 * m4];                 // KEEP 16B load
        f32x2 d01 = *(const f32x2*)&dec_s[g4][4 * m4];
        f32x2 d23 = *(const f32x2*)&dec_s[g4][4 * m4 + 2];
        float4 vv = *(const float4*)&v_s[4 * m4];
        f32x2 e01; e01.x = e4.x; e01.y = e4.y;
        f32x2 e23; e23.x = e4.z; e23.y = e4.w;
        f32x2 t01 = tanh2pk(pk_add(e01, d01));
        f32x2 t23 = tanh2pk(pk_add(e23, d23));
        // strict sequential accumulation over ascending m (scalar chain)
        acc = acc + (vv.x * t01.x);
        acc = acc + (vv.y * t01.y);
        acc = acc + (vv.z * t23.x);
        acc = acc + (vv.w * t23.y);
      }
      masked = acc;                    // mask term is exactly 0.0 for unmasked
      val = gmb + masked;
      ia = sc;
    }
    // wave-local argmax (first-max tie-break on s), max, sum-exp
    {
      float va = val;
      float mx = masked;
#pragma unroll
      for (int off = 32; off > 0; off >>= 1) {
        float vo = __shfl_xor(va, off, 64);
        int io = __shfl_xor(ia, off, 64);
        if (vo > va || (vo == va && io < ia)) { va = vo; ia = io; }
        mx = fmaxf(mx, __shfl_xor(mx, off, 64));
      }
      float se = expf(masked - mx);
#pragma unroll
      for (int off = 32; off > 0; off >>= 1) se = se + __shfl_xor(se, off, 64);
      if (lane == 0) {
        red_va[g4][half] = va; red_ia[g4][half] = ia;
        red_mx[g4][half] = mx; red_se[g4][half] = se;
      }
      ia = active ? sc : 0x7fffffff;   // restore own index for winner check
    }
    __syncthreads();

    float mx2, lse2;
    {
      float vaA = red_va[g4][0], vaB = red_va[g4][1];
      int iaA = red_ia[g4][0], iaB = red_ia[g4][1];
      int loc = (vaB > vaA || (vaB == vaA && iaB < iaA)) ? iaB : iaA;
      if (active && sc == loc) {
        red_msel[g4] = masked;
        tour[(size_t)b4 * 129 + step] = (float)loc;
        if (step == 0) tour[(size_t)b4 * 129 + 128] = (float)loc;
        // O(1) swap-remove loc from compact list
        int p = pos_s[g4][loc];
        int last = cu_s[g4][u - 1];
        cu_s[g4][p] = last;
        pos_s[g4][last] = p;
      }
      // next-step decoder input (all 128 threads of the batch copy)
      const float* er = enc + (size_t)b4 * 16384 + (size_t)loc * 128;
      xI_s[s4][g4] = er[s4];
      // loose log-softmax combine (logp not fed back; threshold 3.32)
      float mxA = red_mx[g4][0], mxB = red_mx[g4][1];
      float seA = red_se[g4][0], seB = red_se[g4][1];
      mx2 = fmaxf(mxA, mxB);
      float se2 = seA * expf(mxA - mx2) + seB * expf(mxB - mx2);
      lse2 = logf(se2);
    }
    __syncthreads();
    logp_sum = logp_sum + ((red_msel[g4] - mx2) - lse2);
  }

  if (half == 0 && lane == 0) out[b4] = logp_sum;
}

// ---------------- host ----------------
extern "C" void kernel_launch(void* const* d_in, const int* in_sizes, int n_in,
                              void* d_out, int out_size, void* d_ws, size_t ws_size,
                              hipStream_t stream) {
  (void)in_sizes; (void)n_in; (void)out_size;
  const float* enc       = (const float*)d_in[0];
  const float* h0        = (const float*)d_in[1];
  const float* c0        = (const float*)d_in[2];
  const float* dec_first = (const float*)d_in[3];
  const float* W_ref     = (const float*)d_in[4];
  const float* W_out     = (const float*)d_in[5];
  const float* v         = (const float*)d_in[6];
  const float* W_ih      = (const float*)d_in[7];
  const float* W_hh      = (const float*)d_in[8];
  const float* b_ih      = (const float*)d_in[9];
  const float* b_hh      = (const float*)d_in[10];

  const size_t encT_elems = (size_t)2048 * 16384;
  size_t need = (encT_elems + 65536 + 65536) * sizeof(float) + 256 * sizeof(uint32_t);
  if (ws_size < need) return;

  float* encT = (float*)d_ws;
  float* WihT = encT + encT_elems;
  float* WhhT = WihT + 65536;
  uint32_t* keys = (uint32_t*)(WhhT + 65536);
  float* out = (float*)d_out;

  k_keys<<<dim3(1), dim3(128), 0, stream>>>(keys);
  k_trans<<<dim3(256), dim3(256), 0, stream>>>(W_ih, W_hh, WihT, WhhT);
  k_encT<<<dim3(4096), dim3(128), 0, stream>>>(enc, W_ref, encT);
  k_main<<<dim3(512), dim3(512), 0, stream>>>(enc, h0, c0, dec_first, W_out, v,
                                              b_ih, b_hh, WihT, WhhT, encT, keys, out);
}

// Round 13
// 5762.489 us; speedup vs baseline: 1.2141x; 1.2141x over previous
//
#include <hip/hip_runtime.h>
#include <cstdint>
#include <cstddef>

#pragma clang fp contract(off)

// ===================== round-to-round toggles =====================
#define PRNG_PARTITIONABLE 1   // confirmed correct in R1 (absmax 0.0)
// sigmoid exp-form; tanh = XLA poly clamp +-9; gemms = sequential-k fmaf;
// score reduce = strict sequential per (b,s) lane; mask compaction (R7);
// fdiv_rn (R6/R8/R11 on-device bit-exact). Bit-exact R1-R12.
// R13: pk-VOP3P refuted twice (R6, R12) — reverted to R11 arithmetic.
// NEW: cross-batch P4 packing — all 4u (batch,entry) units packed onto
// lanes q<4u; waves needed ceil(4u/64) vs per-batch 2/1 (-25% m-loop
// wave-work). Reduction via LDS (order-free comparator unchanged; se's
// masked terms were exactly +0.0f in reference -> dropping bit-exact;
// msel read via pos_s before swap-remove).
// ==================================================================

#define INFTY_F 1.0e8f
#define TINY_F 1.17549435e-38f

// In-range correctly-rounded f32 divide: LLVM's FDIV32 lowering minus
// div_scale/div_fixup (pass-through for normal mid-range operands; here
// q in [4.9e-3, 53], |num| <= 500). On-device bit-exact R6/R8/R11.
__device__ __forceinline__ float fdiv_rn(float n, float q) {
  float y0 = __builtin_amdgcn_rcpf(q);
  float y  = fmaf(fmaf(-q, y0, 1.0f), y0, y0);
  float r0 = n * y;
  float e0 = fmaf(-q, r0, n);
  float r1 = fmaf(e0, y, r0);
  float e1 = fmaf(-q, r1, n);
  return fmaf(e1, y, r1);
}

// ---------------- threefry2x32 (jax exact) ----------------
__device__ __forceinline__ void tf2x32(uint32_t k0, uint32_t k1, uint32_t x0, uint32_t x1,
                                       uint32_t& o0, uint32_t& o1) {
  uint32_t ks2 = k0 ^ k1 ^ 0x1BD11BDAu;
  uint32_t v0 = x0 + k0, v1 = x1 + k1;
#define TF_R(r) { v0 += v1; v1 = (v1 << (r)) | (v1 >> (32 - (r))); v1 ^= v0; }
  TF_R(13) TF_R(15) TF_R(26) TF_R(6)
  v0 += k1;  v1 += ks2 + 1u;
  TF_R(17) TF_R(29) TF_R(16) TF_R(24)
  v0 += ks2; v1 += k0 + 2u;
  TF_R(13) TF_R(15) TF_R(26) TF_R(6)
  v0 += k0;  v1 += k1 + 3u;
  TF_R(17) TF_R(29) TF_R(16) TF_R(24)
  v0 += k1;  v1 += ks2 + 4u;
  TF_R(13) TF_R(15) TF_R(26) TF_R(6)
  v0 += ks2; v1 += k0 + 5u;
#undef TF_R
  o0 = v0; o1 = v1;
}

__device__ __forceinline__ uint32_t random_bits32(uint32_t k0, uint32_t k1, uint32_t j) {
#if PRNG_PARTITIONABLE
  uint32_t o0, o1;
  tf2x32(k0, k1, 0u, j, o0, o1);
  return o0 ^ o1;
#else
  uint32_t o0, o1;
  if (j < 131072u) { tf2x32(k0, k1, j, j + 131072u, o0, o1); return o0; }
  else             { tf2x32(k0, k1, j - 131072u, j, o0, o1); return o1; }
#endif
}

// ---------------- XLA math replicas ----------------
__device__ __forceinline__ float xla_tanhf(float x) {
  float xc = fminf(fmaxf(x, -9.0f), 9.0f);
  float x2 = xc * xc;
  float p = -2.76076847742355e-16f;
  p = (p * x2) + 2.00018790482477e-13f;
  p = (p * x2) + -8.60467152213735e-11f;
  p = (p * x2) + 5.12229709037114e-08f;
  p = (p * x2) + 1.48572235717979e-05f;
  p = (p * x2) + 6.37261928875436e-04f;
  p = (p * x2) + 4.89352455891786e-03f;
  float num = xc * p;
  float q = 1.19825839466702e-06f;
  q = (q * x2) + 1.18534705686654e-04f;
  q = (q * x2) + 2.26843463243900e-03f;
  q = (q * x2) + 4.89352518554385e-03f;
  float r = fdiv_rn(num, q);           // q in [4.9e-3, 53]: verified range
  return (fabsf(x) < 0.0004f) ? x : r;
}

// scalar-pair tanh used in P4; per-element ops IEEE-identical to xla_tanhf.
__device__ __forceinline__ void xla_tanh2(float xa, float xb, float& ra, float& rb) {
  float xca = fminf(fmaxf(xa, -9.0f), 9.0f);
  float xcb = fminf(fmaxf(xb, -9.0f), 9.0f);
  float x2a = xca * xca, x2b = xcb * xcb;
  float pa = -2.76076847742355e-16f, pb = -2.76076847742355e-16f;
  pa = (pa * x2a) + 2.00018790482477e-13f;  pb = (pb * x2b) + 2.00018790482477e-13f;
  pa = (pa * x2a) + -8.60467152213735e-11f; pb = (pb * x2b) + -8.60467152213735e-11f;
  pa = (pa * x2a) + 5.12229709037114e-08f;  pb = (pb * x2b) + 5.12229709037114e-08f;
  pa = (pa * x2a) + 1.48572235717979e-05f;  pb = (pb * x2b) + 1.48572235717979e-05f;
  pa = (pa * x2a) + 6.37261928875436e-04f;  pb = (pb * x2b) + 6.37261928875436e-04f;
  pa = (pa * x2a) + 4.89352455891786e-03f;  pb = (pb * x2b) + 4.89352455891786e-03f;
  float na = xca * pa, nb = xcb * pb;
  float qa = 1.19825839466702e-06f, qb = 1.19825839466702e-06f;
  qa = (qa * x2a) + 1.18534705686654e-04f; qb = (qb * x2b) + 1.18534705686654e-04f;
  qa = (qa * x2a) + 2.26843463243900e-03f; qb = (qb * x2b) + 2.26843463243900e-03f;
  qa = (qa * x2a) + 4.89352518554385e-03f; qb = (qb * x2b) + 4.89352518554385e-03f;
  float da = fdiv_rn(na, qa), db = fdiv_rn(nb, qb);
  ra = (fabsf(xa) < 0.0004f) ? xa : da;
  rb = (fabsf(xb) < 0.0004f) ? xb : db;
}

__device__ __forceinline__ float xla_expf(float x) {
  x = fminf(x, 88.3762626647950f);
  x = fmaxf(x, -88.3762626647949f);
  float m = floorf((x * 1.44269504088896341f) + 0.5f);
  float r = x - (m * 0.693359375f);
  r = r - (m * -2.12194440e-4f);
  float r2 = r * r;
  float y = 1.9875691500E-4f;
  y = (y * r) + 1.3981999507E-3f;
  y = (y * r) + 8.3334519073E-3f;
  y = (y * r) + 4.1665795894E-2f;
  y = (y * r) + 1.6666665459E-1f;
  y = (y * r) + 5.0000001201E-1f;
  y = (y * r2) + r;
  y = y + 1.0f;
  int mi = (int)m;
  float s = __uint_as_float((uint32_t)((mi + 127) << 23));
  return y * s;
}

__device__ __forceinline__ float xla_sigmoidf(float x) {
  return 1.0f / (1.0f + xla_expf(-x));   // keep compiler div (denom can be huge)
}

__device__ __forceinline__ float xla_logf(float x) {
  uint32_t b = __float_as_uint(x);
  float e = (float)((int)(b >> 23) - 126);
  float m = __uint_as_float((b & 0x007fffffu) | 0x3f000000u);
  bool mlt = (m < 0.707106781186547524f);
  float tmp = mlt ? m : 0.0f;
  e = e - (mlt ? 1.0f : 0.0f);
  float xx = (m - 1.0f) + tmp;
  float z = xx * xx;
  float y = 7.0376836292E-2f;
  y = (y * xx) + -1.1514610310E-1f;
  y = (y * xx) + 1.1676998740E-1f;
  y = (y * xx) + -1.2420140846E-1f;
  y = (y * xx) + 1.4249322787E-1f;
  y = (y * xx) + -1.6668057665E-1f;
  y = (y * xx) + 2.0000714765E-1f;
  y = (y * xx) + -2.4999993993E-1f;
  y = (y * xx) + 3.3333331174E-1f;
  y = y * xx;
  y = y * z;
  y = y + (e * -2.12194440e-4f);
  y = y - (z * 0.5f);
  float res = xx + y;
  res = res + (e * 0.693359375f);
  return res;
}

__device__ __forceinline__ float gumbel_from_bits(uint32_t bits) {
  float f = __uint_as_float((bits >> 9) | 0x3f800000u) - 1.0f;
  float u = (f * 1.0f) + TINY_F;
  u = fmaxf(TINY_F, u);
  return -xla_logf(-xla_logf(u));
}

// ---------------- prep kernels ----------------
__global__ void k_keys(uint32_t* __restrict__ keys) {
  int t = threadIdx.x;
  if (t >= 128) return;
#if PRNG_PARTITIONABLE
  uint32_t o0, o1;
  tf2x32(0u, 1234u, 0u, (uint32_t)t, o0, o1);
  keys[2 * t] = o0; keys[2 * t + 1] = o1;
#else
  uint32_t o0, o1, a, bb;
  if (t < 64) {
    tf2x32(0u, 1234u, (uint32_t)(2 * t),     (uint32_t)(128 + 2 * t), o0, o1); a  = o0;
    tf2x32(0u, 1234u, (uint32_t)(2 * t + 1), (uint32_t)(129 + 2 * t), o0, o1); bb = o0;
  } else {
    tf2x32(0u, 1234u, (uint32_t)(2 * t - 128), (uint32_t)(2 * t),     o0, o1); a  = o1;
    tf2x32(0u, 1234u, (uint32_t)(2 * t - 127), (uint32_t)(2 * t + 1), o0, o1); bb = o1;
  }
  keys[2 * t] = a; keys[2 * t + 1] = bb;
#endif
}

__global__ void k_trans(const float* __restrict__ Wih, const float* __restrict__ Whh,
                        float* __restrict__ WihT, float* __restrict__ WhhT) {
  int idx = blockIdx.x * blockDim.x + threadIdx.x;
  if (idx < 65536) {
    int r = idx >> 7, k = idx & 127;
    WihT[k * 512 + r] = Wih[idx];
    WhhT[k * 512 + r] = Whh[idx];
  }
}

// enc_term[b][s][m] = sum_n enc[b][s][n] * Wref[m][n], sequential-n fmaf.
__global__ __launch_bounds__(128) void k_encT(const float* __restrict__ enc,
                                              const float* __restrict__ Wref,
                                              float* __restrict__ encT) {
  __shared__ float el[64 * 132];
  __shared__ float ot[64 * 129];
  int tid = threadIdx.x;
  int b  = blockIdx.x >> 1;
  int sh = blockIdx.x & 1;
  const float* eb = enc + (size_t)b * 16384 + (size_t)sh * 8192;
  for (int i = tid; i < 8192; i += 128) {
    int s = i >> 7, n = i & 127;
    el[s * 132 + n] = eb[i];
  }
  __syncthreads();
  int sl = tid & 63;
  int mh = tid >> 6;
  for (int ml = 0; ml < 64; ++ml) {
    int m = mh * 64 + ml;
    const float4* wr = (const float4*)(Wref + m * 128);   // wave-broadcast reads
    float acc = 0.0f;
#pragma unroll 8
    for (int q = 0; q < 32; ++q) {
      float4 w4 = wr[q];
      float4 e4 = *(const float4*)&el[sl * 132 + 4 * q];
      acc = fmaf(e4.x, w4.x, acc); acc = fmaf(e4.y, w4.y, acc);
      acc = fmaf(e4.z, w4.z, acc); acc = fmaf(e4.w, w4.w, acc);
    }
    ot[sl * 129 + m] = acc;
  }
  __syncthreads();
  float* op = encT + (size_t)b * 16384 + (size_t)(sh * 64) * 128;
  for (int i = tid; i < 8192; i += 128)
    op[i] = ot[(i >> 7) * 129 + (i & 127)];
}

// ---------------- main decode kernel (4 batches/block, packed P4) ----------
__global__ __launch_bounds__(512, 4) void k_main(
    const float* __restrict__ enc, const float* __restrict__ h0,
    const float* __restrict__ c0, const float* __restrict__ dec_first,
    const float* __restrict__ W_out, const float* __restrict__ v,
    const float* __restrict__ b_ih, const float* __restrict__ b_hh,
    const float* __restrict__ WihT, const float* __restrict__ WhhT,
    const float* __restrict__ encT, const uint32_t* __restrict__ keys,
    float* __restrict__ out) {
  // xI[k][0..3] = inp[g][k], xI[k][4..7] = h[g][k]  (broadcast-read in P1/P3)
  __shared__ float xI_s[128][8];
  __shared__ float c_s[4][128];
  __shared__ float gates_s[4][512];
  __shared__ float2 vdec2_s[4][128];   // (v[m], dec[m]) pairs
  __shared__ float bih_s[512];
  __shared__ float bhh_s[512];
  __shared__ float v_s[128];
  __shared__ uint32_t keys_s[256];
  __shared__ int cu_s[4][128];         // compact list of unmasked positions
  __shared__ int pos_s[4][128];        // inverse: pos_s[g][s] = index in cu_s
  __shared__ float val_s[512];         // per-unit gumbel+score
  __shared__ float msk_s[512];         // per-unit masked score
  __shared__ int   sc_s[512];          // per-unit position
  __shared__ int   loc_s[4];           // sampled loc per batch

  const int tid  = threadIdx.x;
  const int lane = tid & 63;
  const int w    = tid >> 6;         // wave 0..7
  const int g4   = w >> 1;           // batch slot for update phase
  const int half = w & 1;
  const int s4   = half * 64 + lane; // copy position in update phase
  const int bbase = blockIdx.x * 4;
  const int b4   = bbase + g4;

  // ---- init ----
  bih_s[tid] = b_ih[tid];
  bhh_s[tid] = b_hh[tid];
  if (tid < 256) keys_s[tid] = keys[tid];
  if (tid < 128) v_s[tid] = v[tid];
  {
    int g = tid >> 7, j = tid & 127;
    xI_s[j][g]     = dec_first[j];
    xI_s[j][4 + g] = h0[(size_t)(bbase + g) * 128 + j];
    c_s[g][j] = c0[(size_t)(bbase + g) * 128 + j];
    cu_s[g][j] = j;
    pos_s[g][j] = j;
  }
  float logp_sum = 0.0f;
  float* tour = out + 2048;
  __syncthreads();

  for (int step = 0; step < 128; ++step) {
    // ---- P1: gates = ((inp@WihT + b_ih) + h@WhhT) + b_hh, sequential-k fmaf
    {
      const int r = tid;
      float aA0 = 0.0f, aA1 = 0.0f, aA2 = 0.0f, aA3 = 0.0f;
      float aB0 = 0.0f, aB1 = 0.0f, aB2 = 0.0f, aB3 = 0.0f;
      const float* pih = WihT + r;
      const float* phh = WhhT + r;
#pragma unroll 8
      for (int k = 0; k < 128; ++k) {
        float4 xi = *(const float4*)&xI_s[k][0];
        float4 xh = *(const float4*)&xI_s[k][4];
        float wih = pih[k * 512], whh = phh[k * 512];
        aA0 = fmaf(xi.x, wih, aA0);
        aA1 = fmaf(xi.y, wih, aA1);
        aA2 = fmaf(xi.z, wih, aA2);
        aA3 = fmaf(xi.w, wih, aA3);
        aB0 = fmaf(xh.x, whh, aB0);
        aB1 = fmaf(xh.y, whh, aB1);
        aB2 = fmaf(xh.z, whh, aB2);
        aB3 = fmaf(xh.w, whh, aB3);
      }
      float b1 = bih_s[r], b2 = bhh_s[r];
      gates_s[0][r] = (((aA0 + b1) + aB0) + b2);
      gates_s[1][r] = (((aA1 + b1) + aB1) + b2);
      gates_s[2][r] = (((aA2 + b1) + aB2) + b2);
      gates_s[3][r] = (((aA3 + b1) + aB3) + b2);
    }
    __syncthreads();

    // ---- P2: LSTM cell (exact op order), one (g,j) per thread
    {
      int g = tid >> 7, j = tid & 127;
      float gi = gates_s[g][j], gf = gates_s[g][128 + j];
      float gg = gates_s[g][256 + j], go = gates_s[g][384 + j];
      float si = xla_sigmoidf(gi), sf = xla_sigmoidf(gf), so = xla_sigmoidf(go);
      float gt = xla_tanhf(gg);
      float cold = c_s[g][j];
      float cn = (sf * cold) + (si * gt);
      c_s[g][j] = cn;
      xI_s[j][4 + g] = so * xla_tanhf(cn);
    }
    __syncthreads();

    // ---- P3: dec[g][m] = sum_k h[g][k]*W_out[k][m], sequential-k fmaf
    {
      int g = tid >> 7, m = tid & 127;
      float acc = 0.0f;
      const float* wo = W_out + m;
#pragma unroll 8
      for (int k = 0; k < 128; ++k)
        acc = fmaf(xI_s[k][4 + g], wo[k * 128], acc);
      vdec2_s[g][m] = make_float2(v_s[m], acc);
    }
    __syncthreads();

    // ---- P4a: packed units q = batch*u + entry, q < 4u. Each active lane
    // computes its (batch, position) score (exact sequential m-chain) + gumbel.
    const int u = 128 - step;          // unmasked count (uniform)
    {
      const int q = tid;
      float masked = -INFTY_F, val = -INFTY_F;
      int sc = 0x7fffffff;
      if (q < 4 * u) {
        int bq = (q >= u) + (q >= 2 * u) + (q >= 3 * u);
        int e  = q - bq * u;
        sc = cu_s[bq][e];
        const int bb = bbase + bq;
        // gumbel first: pure ALU, overlaps the first e4 load window
        uint32_t kk0 = keys_s[2 * step], kk1 = keys_s[2 * step + 1];
        uint32_t j0 = (uint32_t)bb * 128u + (uint32_t)sc;
        float gmb = gumbel_from_bits(random_bits32(kk0, kk1, j0));
        const float* ep = encT + ((size_t)bb * 128 + (size_t)sc) * 128;
        float acc = 0.0f;
#pragma unroll 8
        for (int m4 = 0; m4 < 32; ++m4) {
          float4 e4 = *(const float4*)&ep[4 * m4];
          float4 vd01 = *(const float4*)&vdec2_s[bq][4 * m4];      // v0,d0,v1,d1
          float4 vd23 = *(const float4*)&vdec2_s[bq][4 * m4 + 2];  // v2,d2,v3,d3
          float t0, t1, t2, t3;
          xla_tanh2(e4.x + vd01.y, e4.y + vd01.w, t0, t1);
          xla_tanh2(e4.z + vd23.y, e4.w + vd23.w, t2, t3);
          // strict sequential accumulation over ascending m (scalar chain)
          acc = acc + (vd01.x * t0);
          acc = acc + (vd01.z * t1);
          acc = acc + (vd23.x * t2);
          acc = acc + (vd23.z * t3);
        }
        masked = acc;                  // mask term is exactly 0.0 for unmasked
        val = gmb + masked;
      }
      val_s[q] = val;
      msk_s[q] = masked;
      sc_s[q]  = sc;
    }
    __syncthreads();

    // ---- P4b: per-batch reduce (waves 0..3, batch = w). Order-free argmax
    // comparator; se over unmasked only (masked terms were exactly +0.0f).
    if (w < 4) {
      const int g = w;
      const int base = g * u;
      float vaA = -INFTY_F, mkA = -INFTY_F;
      float vaB = -INFTY_F, mkB = -INFTY_F;
      int iaA = 0x7fffffff, iaB = 0x7fffffff;
      if (lane < u)      { vaA = val_s[base + lane];      iaA = sc_s[base + lane];      mkA = msk_s[base + lane]; }
      if (lane + 64 < u) { vaB = val_s[base + lane + 64]; iaB = sc_s[base + lane + 64]; mkB = msk_s[base + lane + 64]; }
      float va = vaA; int ia = iaA;
      if (vaB > va || (vaB == va && iaB < ia)) { va = vaB; ia = iaB; }
      float mx = fmaxf(mkA, mkB);
      float se = 0.0f;
#pragma unroll
      for (int off = 32; off > 0; off >>= 1) {
        float vo = __shfl_xor(va, off, 64);
        int io = __shfl_xor(ia, off, 64);
        if (vo > va || (vo == va && io < ia)) { va = vo; ia = io; }
        mx = fmaxf(mx, __shfl_xor(mx, off, 64));
      }
      if (lane < u)      se = se + expf(mkA - mx);
      if (lane + 64 < u) se = se + expf(mkB - mx);
#pragma unroll
      for (int off = 32; off > 0; off >>= 1) se = se + __shfl_xor(se, off, 64);
      const int loc = ia;              // uniform across wave after reduce
      // msel: read loc's list position BEFORE swap-remove (wave-sequential)
      int p = pos_s[g][loc];
      float msel = msk_s[base + p];
      if (lane == 0) {
        loc_s[g] = loc;
        tour[(size_t)(bbase + g) * 129 + step] = (float)loc;
        if (step == 0) tour[(size_t)(bbase + g) * 129 + 128] = (float)loc;
        // O(1) swap-remove loc from compact list
        int last = cu_s[g][u - 1];
        cu_s[g][p] = last;
        pos_s[g][last] = p;
      }
      // loose log-softmax (logp not fed back; threshold 3.32)
      float lse = logf(se);
      logp_sum = logp_sum + ((msel - mx) - lse);
    }
    __syncthreads();

    // ---- update: next-step decoder input (original (g4,half) mapping)
    {
      const int loc = loc_s[g4];
      const float* er = enc + (size_t)b4 * 16384 + (size_t)loc * 128;
      xI_s[s4][g4] = er[s4];
    }
    __syncthreads();
  }

  if (w < 4 && lane == 0) out[bbase + w] = logp_sum;
}

// ---------------- host ----------------
extern "C" void kernel_launch(void* const* d_in, const int* in_sizes, int n_in,
                              void* d_out, int out_size, void* d_ws, size_t ws_size,
                              hipStream_t stream) {
  (void)in_sizes; (void)n_in; (void)out_size;
  const float* enc       = (const float*)d_in[0];
  const float* h0        = (const float*)d_in[1];
  const float* c0        = (const float*)d_in[2];
  const float* dec_first = (const float*)d_in[3];
  const float* W_ref     = (const float*)d_in[4];
  const float* W_out     = (const float*)d_in[5];
  const float* v         = (const float*)d_in[6];
  const float* W_ih      = (const float*)d_in[7];
  const float* W_hh      = (const float*)d_in[8];
  const float* b_ih      = (const float*)d_in[9];
  const float* b_hh      = (const float*)d_in[10];

  const size_t encT_elems = (size_t)2048 * 16384;
  size_t need = (encT_elems + 65536 + 65536) * sizeof(float) + 256 * sizeof(uint32_t);
  if (ws_size < need) return;

  float* encT = (float*)d_ws;
  float* WihT = encT + encT_elems;
  float* WhhT = WihT + 65536;
  uint32_t* keys = (uint32_t*)(WhhT + 65536);
  float* out = (float*)d_out;

  k_keys<<<dim3(1), dim3(128), 0, stream>>>(keys);
  k_trans<<<dim3(256), dim3(256), 0, stream>>>(W_ih, W_hh, WihT, WhhT);
  k_encT<<<dim3(4096), dim3(128), 0, stream>>>(enc, W_ref, encT);
  k_main<<<dim3(512), dim3(512), 0, stream>>>(enc, h0, c0, dec_first, W_out, v,
                                              b_ih, b_hh, WihT, WhhT, encT, keys, out);
}